// Round 7
// baseline (476.095 us; speedup 1.0000x reference)
//
#include <hip/hip_runtime.h>

#define HID 128
#define NPG 1000
#define NGRAPH 100
#define NNODES (NPG * NGRAPH)      // 100000
#define DEG 8
#define LN_EPS 1e-5f

// ---------------------------------------------------------------------------
// K1: h = relu(x[0:2N] @ W^T + b) via split-fp16 MFMA (3-term: hi*hi + lo*hi
// + hi*lo, fp32 accumulate -> ~2^-22 relative error, fp32-equivalent here).
// S rows (r < N) -> outS (= out), I rows (r >= N) -> outI (= d_ws).
// Fused path: also zero-inits the CSR cnt word of out row 2N+n (one 4B store
// for 100k of the 400k threads) so k_edges can atomicAdd into it.
// ~55 us, near its 49 us roofline.
// ---------------------------------------------------------------------------
#define K1_ROWS 128

typedef _Float16 half8 __attribute__((ext_vector_type(8)));
typedef float f32x4 __attribute__((ext_vector_type(4)));

__device__ inline void cvt_split(const float4 a, const float4 b,
                                 half8& hi, half8& lo)
{
    float v[8] = {a.x, a.y, a.z, a.w, b.x, b.y, b.z, b.w};
    #pragma unroll
    for (int i = 0; i < 8; ++i) {
        _Float16 h = (_Float16)v[i];          // RNE
        hi[i] = h;
        lo[i] = (_Float16)(v[i] - (float)h);  // remainder exact in f32
    }
}

__global__ __launch_bounds__(256, 2) void k_gemm_relu(
    const float* __restrict__ x, const float* __restrict__ W,
    const float* __restrict__ bias, float* __restrict__ outS,
    float* __restrict__ outI, float* __restrict__ csr_base, int nrows)
{
    __shared__ alignas(16) _Float16 Xh[K1_ROWS * 64];
    __shared__ alignas(16) _Float16 Xl[K1_ROWS * 64];
    __shared__ alignas(16) _Float16 Wh[HID * 64];
    __shared__ alignas(16) _Float16 Wl[HID * 64];

    const int tid  = threadIdx.x;
    const int lane = tid & 63;
    const int w    = tid >> 6;
    const int wr   = (w >> 1) * 64;   // wave row offset in tile
    const int wc   = (w & 1) * 64;    // wave col offset
    const int r0   = blockIdx.x * K1_ROWS;

    // zero CSR cnt words (fused path only)
    if (csr_base != nullptr) {
        int nid = blockIdx.x * 256 + tid;
        if (nid < NNODES)
            *reinterpret_cast<int*>(&csr_base[(size_t)nid * HID]) = 0;
    }

    f32x4 acc[4][4];
    #pragma unroll
    for (int i = 0; i < 4; ++i)
        #pragma unroll
        for (int j = 0; j < 4; ++j)
            acc[i][j] = (f32x4){0.f, 0.f, 0.f, 0.f};

    const int l15 = lane & 15;
    const int lg  = lane >> 4;       // k-group 0..3
    const int swz = (lane & 7) << 3; // row&7 == lane&7 for all frag rows/cols

    for (int kh = 0; kh < 2; ++kh) {
        if (kh) __syncthreads();

        // ---- stage X half-tile: 128 rows x 64 k, fp32 -> (hi,lo) f16 ----
        #pragma unroll
        for (int it = 0; it < 4; ++it) {
            int chunk = tid + it * 256;      // 1024 chunks of 8 halves
            int row = chunk >> 3, kg = chunk & 7;
            const float* gp = &x[(size_t)(r0 + row) * HID + kh * 64 + kg * 8];
            float4 a = reinterpret_cast<const float4*>(gp)[0];
            float4 b = reinterpret_cast<const float4*>(gp)[1];
            half8 hi, lo; cvt_split(a, b, hi, lo);
            int widx = (row * 64 + kg * 8) ^ ((row & 7) << 3);
            *reinterpret_cast<half8*>(&Xh[widx]) = hi;
            *reinterpret_cast<half8*>(&Xl[widx]) = lo;
        }
        // ---- stage W half-tile: 128 out-cols x 64 k ----
        #pragma unroll
        for (int it = 0; it < 4; ++it) {
            int chunk = tid + it * 256;
            int row = chunk >> 3, kg = chunk & 7;
            const float* gp = &W[(size_t)row * HID + kh * 64 + kg * 8];
            float4 a = reinterpret_cast<const float4*>(gp)[0];
            float4 b = reinterpret_cast<const float4*>(gp)[1];
            half8 hi, lo; cvt_split(a, b, hi, lo);
            int widx = (row * 64 + kg * 8) ^ ((row & 7) << 3);
            *reinterpret_cast<half8*>(&Wh[widx]) = hi;
            *reinterpret_cast<half8*>(&Wl[widx]) = lo;
        }
        __syncthreads();

        // ---- compute: 2 kb-steps of K=32, 48 MFMA each ----
        #pragma unroll
        for (int kb = 0; kb < 2; ++kb) {
            half8 ah[4], al[4], bh[4], bl[4];
            #pragma unroll
            for (int t = 0; t < 4; ++t) {
                int arow = wr + t * 16 + l15;
                int aidx = (arow * 64 + kb * 32 + lg * 8) ^ swz;
                ah[t] = *reinterpret_cast<const half8*>(&Xh[aidx]);
                al[t] = *reinterpret_cast<const half8*>(&Xl[aidx]);
                int bcol = wc + t * 16 + l15;
                int bidx = (bcol * 64 + kb * 32 + lg * 8) ^ swz;
                bh[t] = *reinterpret_cast<const half8*>(&Wh[bidx]);
                bl[t] = *reinterpret_cast<const half8*>(&Wl[bidx]);
            }
            #pragma unroll
            for (int rt = 0; rt < 4; ++rt)
                #pragma unroll
                for (int ct = 0; ct < 4; ++ct) {
                    acc[rt][ct] = __builtin_amdgcn_mfma_f32_16x16x32_f16(
                        ah[rt], bh[ct], acc[rt][ct], 0, 0, 0);
                    acc[rt][ct] = __builtin_amdgcn_mfma_f32_16x16x32_f16(
                        al[rt], bh[ct], acc[rt][ct], 0, 0, 0);
                    acc[rt][ct] = __builtin_amdgcn_mfma_f32_16x16x32_f16(
                        ah[rt], bl[ct], acc[rt][ct], 0, 0, 0);
                }
        }
    }

    // ---- epilogue: bias + relu + store (64B-coalesced per 16-lane group) ----
    float bc[4];
    #pragma unroll
    for (int ct = 0; ct < 4; ++ct) bc[ct] = bias[wc + ct * 16 + l15];

    #pragma unroll
    for (int rt = 0; rt < 4; ++rt) {
        int rowb = r0 + wr + rt * 16 + lg * 4;
        #pragma unroll
        for (int j = 0; j < 4; ++j) {
            int r = rowb + j;
            if (r < nrows) {
                float* base = (r < NNODES)
                                  ? &outS[(size_t)r * HID]
                                  : &outI[(size_t)(r - NNODES) * HID];
                float* hp = base + wc + l15;
                #pragma unroll
                for (int ct = 0; ct < 4; ++ct)
                    hp[ct * 16] = fmaxf(acc[rt][ct][j] + bc[ct], 0.f);
            }
        }
    }
}

// ---------------------------------------------------------------------------
// K2a: edge-centric global CSR build.  CSR for node n lives in out row 2N+n
// (512B): int cnt at slot 0, cols at slots 4..67 (int4-aligned).  One
// device-scope atomicAdd per edge assigns the slot; order nondeterminism only
// permutes the fp32 gather sum (within tolerance, same as previous rounds).
// The dR region is safe: row 2N+n is consumed (gather) by its owning
// half-wave in K2b before that same half-wave overwrites it with ln(dR).
// ---------------------------------------------------------------------------
__global__ __launch_bounds__(256) void k_edges(
    const int* __restrict__ erow, const int* __restrict__ ecol,
    float* __restrict__ csr_base)
{
    const int e4 = (blockIdx.x * 256 + threadIdx.x) * 4;
    if (e4 >= NNODES * DEG) return;
    int4 rr = *reinterpret_cast<const int4*>(&erow[e4]);
    int4 cc = *reinterpret_cast<const int4*>(&ecol[e4]);
    #pragma unroll
    for (int u = 0; u < 4; ++u) {
        int r = (u == 0) ? rr.x : (u == 1) ? rr.y : (u == 2) ? rr.z : rr.w;
        int c = (u == 0) ? cc.x : (u == 1) ? cc.y : (u == 2) ? cc.z : cc.w;
        unsigned* cnt = reinterpret_cast<unsigned*>(&csr_base[(size_t)r * HID]);
        unsigned slot = atomicAdd(cnt, 1u);
        if (slot < 64u) reinterpret_cast<int*>(cnt)[4 + slot] = (int)c;
    }
}

// ---------------------------------------------------------------------------
// K2b: one node per 32-lane half-wave; no LDS, no barriers, no atomics.
// 12500 blocks x 256 threads (8 nodes/block) -> occupancy bounded only by
// VGPR (launch_bounds(256,8)); ~48 blocks/CU kills the tail.
// Per node, 6 independent loads issue up front: cnt + CSR chunks 0,1
// (speculative -- always within the 512B row, addresses independent of cnt),
// S row, I row, tail row.  Tail chunks use masked weights (no branches on
// garbage cols).  Fused ln3 (exact 2-pass, 10 shfl rounds for 3 rows).
// Bijective XCD swizzle (12500 = 8*1562+4) keeps each graph's 125 blocks on
// one XCD -> its 512KB I-slice is L2-resident after first touch.
// ---------------------------------------------------------------------------
__global__ __launch_bounds__(256, 8) void k_gather_ln(
    const float* __restrict__ x, const float* __restrict__ Ibuf,
    const float* __restrict__ lnw, const float* __restrict__ lnb,
    float* __restrict__ out)
{
    const int bi   = blockIdx.x;
    const int xcd  = bi & 7, slt = bi >> 3;
    // q=1562, r=4: xcd<4 own 1563 slots, else 1562 (bijective, m204 form)
    const int id   = ((xcd < 4) ? xcd * 1563 : 4 * 1563 + (xcd - 4) * 1562) + slt;

    const int tid  = threadIdx.x;
    const int wave = tid >> 6, lane = tid & 63;
    const int h    = lane >> 5;
    const int l32  = lane & 31;
    const int c4   = l32 * 4;
    const size_t N = NNODES;
    const size_t gn = (size_t)id * 8 + wave * 2 + h;   // node id, < 100000

    const int* csr = reinterpret_cast<const int*>(&out[(2 * N + gn) * HID]);

    // issue 6 independent loads immediately
    int  cntw = csr[0];
    int4 ch0  = *reinterpret_cast<const int4*>(&csr[4]);
    int4 ch1  = *reinterpret_cast<const int4*>(&csr[8]);
    float4 Sv = *reinterpret_cast<const float4*>(&out[gn * HID + c4]);
    float4 Iv = *reinterpret_cast<const float4*>(&Ibuf[gn * HID + c4]);
    float4 T  = *reinterpret_cast<const float4*>(&x[(3 * N + gn) * HID + c4]);

    const int deg = min(cntw, 64);

    float ax = 0.f, ay = 0.f, az = 0.f, aw = 0.f;

    // masked 4-wide chunk processor (deg uniform per half-wave)
    auto proc = [&](int4 cc, int j) {
        int  i0 = (j + 0 < deg) ? cc.x : 0;  float w0 = (j + 0 < deg) ? 1.f : 0.f;
        int  i1 = (j + 1 < deg) ? cc.y : 0;  float w1 = (j + 1 < deg) ? 1.f : 0.f;
        int  i2 = (j + 2 < deg) ? cc.z : 0;  float w2 = (j + 2 < deg) ? 1.f : 0.f;
        int  i3 = (j + 3 < deg) ? cc.w : 0;  float w3 = (j + 3 < deg) ? 1.f : 0.f;
        float4 v0 = *reinterpret_cast<const float4*>(&Ibuf[(size_t)i0 * HID + c4]);
        float4 v1 = *reinterpret_cast<const float4*>(&Ibuf[(size_t)i1 * HID + c4]);
        float4 v2 = *reinterpret_cast<const float4*>(&Ibuf[(size_t)i2 * HID + c4]);
        float4 v3 = *reinterpret_cast<const float4*>(&Ibuf[(size_t)i3 * HID + c4]);
        ax += w0 * v0.x + w1 * v1.x + w2 * v2.x + w3 * v3.x;
        ay += w0 * v0.y + w1 * v1.y + w2 * v2.y + w3 * v3.y;
        az += w0 * v0.z + w1 * v1.z + w2 * v2.z + w3 * v3.z;
        aw += w0 * v0.w + w1 * v1.w + w2 * v2.w + w3 * v3.w;
    };

    if (deg > 0) proc(ch0, 0);
    if (deg > 4) proc(ch1, 4);
    #pragma unroll 1
    for (int j = 8; j < deg; j += 4) {
        int4 cc = *reinterpret_cast<const int4*>(&csr[4 + j]);
        proc(cc, j);
    }

    // beta/gam = cols 0,1 of tail row = this half's lane 0 (lane h*32)
    const float beta = __shfl(T.x, h << 5);
    const float gam  = __shfl(T.y, h << 5);

    float4 dS, dI, dR;
    dS.x = -beta * (ax * Sv.x);
    dS.y = -beta * (ay * Sv.y);
    dS.z = -beta * (az * Sv.z);
    dS.w = -beta * (aw * Sv.w);
    dI.x = -dS.x - gam * Iv.x;
    dI.y = -dS.y - gam * Iv.y;
    dI.z = -dS.z - gam * Iv.z;
    dI.w = -dS.w - gam * Iv.w;
    dR.x = gam * Iv.x;
    dR.y = gam * Iv.y;
    dR.z = gam * Iv.z;
    dR.w = gam * Iv.w;

    const float4 lwv = *reinterpret_cast<const float4*>(&lnw[c4]);
    const float4 lbv = *reinterpret_cast<const float4*>(&lnb[c4]);

    // fused 3-row LayerNorm: 3 pipelined 32-lane shuffle chains, exact 2-pass
    float sA = dS.x + dS.y + dS.z + dS.w;
    float sB = dI.x + dI.y + dI.z + dI.w;
    float sC = dR.x + dR.y + dR.z + dR.w;
    #pragma unroll
    for (int m = 1; m < 32; m <<= 1) {
        sA += __shfl_xor(sA, m);
        sB += __shfl_xor(sB, m);
        sC += __shfl_xor(sC, m);
    }
    const float mA = sA * (1.f / 128.f);
    const float mB = sB * (1.f / 128.f);
    const float mC = sC * (1.f / 128.f);
    float qA = (dS.x-mA)*(dS.x-mA) + (dS.y-mA)*(dS.y-mA)
             + (dS.z-mA)*(dS.z-mA) + (dS.w-mA)*(dS.w-mA);
    float qB = (dI.x-mB)*(dI.x-mB) + (dI.y-mB)*(dI.y-mB)
             + (dI.z-mB)*(dI.z-mB) + (dI.w-mB)*(dI.w-mB);
    float qC = (dR.x-mC)*(dR.x-mC) + (dR.y-mC)*(dR.y-mC)
             + (dR.z-mC)*(dR.z-mC) + (dR.w-mC)*(dR.w-mC);
    #pragma unroll
    for (int m = 1; m < 32; m <<= 1) {
        qA += __shfl_xor(qA, m);
        qB += __shfl_xor(qB, m);
        qC += __shfl_xor(qC, m);
    }
    const float rsA = rsqrtf(qA * (1.f / 128.f) + LN_EPS);
    const float rsB = rsqrtf(qB * (1.f / 128.f) + LN_EPS);
    const float rsC = rsqrtf(qC * (1.f / 128.f) + LN_EPS);

    float4 o;
    o.x = (dS.x - mA) * rsA * lwv.x + lbv.x;
    o.y = (dS.y - mA) * rsA * lwv.y + lbv.y;
    o.z = (dS.z - mA) * rsA * lwv.z + lbv.z;
    o.w = (dS.w - mA) * rsA * lwv.w + lbv.w;
    *reinterpret_cast<float4*>(&out[gn * HID + c4]) = o;
    o.x = (dI.x - mB) * rsB * lwv.x + lbv.x;
    o.y = (dI.y - mB) * rsB * lwv.y + lbv.y;
    o.z = (dI.z - mB) * rsB * lwv.z + lbv.z;
    o.w = (dI.w - mB) * rsB * lwv.w + lbv.w;
    *reinterpret_cast<float4*>(&out[(N + gn) * HID + c4]) = o;
    o.x = (dR.x - mC) * rsC * lwv.x + lbv.x;
    o.y = (dR.y - mC) * rsC * lwv.y + lbv.y;
    o.z = (dR.z - mC) * rsC * lwv.z + lbv.z;
    o.w = (dR.w - mC) * rsC * lwv.w + lbv.w;
    *reinterpret_cast<float4*>(&out[(2 * N + gn) * HID + c4]) = o;
    *reinterpret_cast<float4*>(&out[(3 * N + gn) * HID + c4]) = T;
}

// ---------------------------------------------------------------------------
// Fallback path (ws too small): original K2 (AI materialized) + K3.
// ---------------------------------------------------------------------------
#define BPG  8
#define RPB  (NPG / BPG)    // 125
#define ECAP 1280

__global__ __launch_bounds__(256) void k_aggregate(
    const float* __restrict__ I, const int* __restrict__ erow,
    const int* __restrict__ ecol, float* __restrict__ AI)
{
    __shared__ int cnt[RPB];
    __shared__ int wp[RPB];
    __shared__ int scan[256];
    __shared__ int cols[ECAP];

    const int g     = blockIdx.x / BPG;
    const int q     = blockIdx.x % BPG;
    const int row0  = q * RPB;
    const int nbase = g * NPG;
    const int ebase = g * (NPG * DEG);
    const int tid   = threadIdx.x;

    if (tid < RPB) cnt[tid] = 0;
    __syncthreads();

    for (int e = tid; e < NPG * DEG; e += 256) {
        int rl = erow[ebase + e] - nbase - row0;
        if ((unsigned)rl < (unsigned)RPB) atomicAdd(&cnt[rl], 1);
    }
    __syncthreads();

    int v = (tid < RPB) ? cnt[tid] : 0;
    scan[tid] = v;
    __syncthreads();
    #pragma unroll
    for (int s = 1; s < 256; s <<= 1) {
        int t = (tid >= s) ? scan[tid - s] : 0;
        __syncthreads();
        scan[tid] += t;
        __syncthreads();
    }
    if (tid < RPB) wp[tid] = scan[tid] - cnt[tid];
    __syncthreads();

    for (int e = tid; e < NPG * DEG; e += 256) {
        int rl = erow[ebase + e] - nbase - row0;
        if ((unsigned)rl < (unsigned)RPB) {
            int p = atomicAdd(&wp[rl], 1);
            if (p < ECAP) cols[p] = ecol[ebase + e];
        }
    }
    __syncthreads();

    const int wave = tid >> 6, lane = tid & 63;
    const int c = lane * 2;
    for (int n = wave; n < RPB; n += 4) {
        int deg = cnt[n];
        int end = wp[n];
        int j   = end - deg;
        float ax = 0.f, ay = 0.f;
        for (; j + 4 <= end; j += 4) {
            int c0 = cols[j], c1 = cols[j + 1], c2 = cols[j + 2], c3 = cols[j + 3];
            float2 v0 = *reinterpret_cast<const float2*>(&I[(size_t)c0 * HID + c]);
            float2 v1 = *reinterpret_cast<const float2*>(&I[(size_t)c1 * HID + c]);
            float2 v2 = *reinterpret_cast<const float2*>(&I[(size_t)c2 * HID + c]);
            float2 v3 = *reinterpret_cast<const float2*>(&I[(size_t)c3 * HID + c]);
            ax += v0.x + v1.x + v2.x + v3.x;
            ay += v0.y + v1.y + v2.y + v3.y;
        }
        for (; j < end; j++) {
            float2 v0 = *reinterpret_cast<const float2*>(&I[(size_t)cols[j] * HID + c]);
            ax += v0.x; ay += v0.y;
        }
        float2 o; o.x = ax; o.y = ay;
        *reinterpret_cast<float2*>(&AI[(size_t)(nbase + row0 + n) * HID + c]) = o;
    }
}

__global__ __launch_bounds__(256) void k_final(
    const float* __restrict__ x, const float* __restrict__ lnw,
    const float* __restrict__ lnb, float* __restrict__ out)
{
    const int wave = threadIdx.x >> 6;
    const int lane = threadIdx.x & 63;
    const size_t i = (size_t)blockIdx.x * 4 + wave;
    const int c    = lane * 2;
    const size_t N = NNODES;

    float2 S  = *reinterpret_cast<const float2*>(&out[i * HID + c]);
    float2 I2 = *reinterpret_cast<const float2*>(&out[(N + i) * HID + c]);
    float2 A  = *reinterpret_cast<const float2*>(&out[(2 * N + i) * HID + c]);

    const float beta = x[(3 * N + i) * HID + 0];
    const float gam  = x[(3 * N + i) * HID + 1];

    float2 dS, dI, dR;
    dS.x = -beta * (A.x * S.x);
    dS.y = -beta * (A.y * S.y);
    dI.x = -dS.x - gam * I2.x;
    dI.y = -dS.y - gam * I2.y;
    dR.x = gam * I2.x;
    dR.y = gam * I2.y;

    const float2 lw = *reinterpret_cast<const float2*>(&lnw[c]);
    const float2 lb = *reinterpret_cast<const float2*>(&lnb[c]);

    auto ln_store = [&](float2 v, float* dst) {
        float s = v.x + v.y;
        #pragma unroll
        for (int m = 1; m < 64; m <<= 1) s += __shfl_xor(s, m);
        const float mean = s * (1.f / 128.f);
        const float dx = v.x - mean, dy = v.y - mean;
        float q = dx * dx + dy * dy;
        #pragma unroll
        for (int m = 1; m < 64; m <<= 1) q += __shfl_xor(q, m);
        const float rs = rsqrtf(q * (1.f / 128.f) + LN_EPS);
        float2 o;
        o.x = dx * rs * lw.x + lb.x;
        o.y = dy * rs * lw.y + lb.y;
        *reinterpret_cast<float2*>(dst) = o;
    };

    ln_store(dS, &out[i * HID + c]);
    ln_store(dI, &out[(N + i) * HID + c]);
    ln_store(dR, &out[(2 * N + i) * HID + c]);

    const float2 t2 =
        *reinterpret_cast<const float2*>(&x[(3 * N + i) * HID + c]);
    *reinterpret_cast<float2*>(&out[(3 * N + i) * HID + c]) = t2;
}

// ---------------------------------------------------------------------------
extern "C" void kernel_launch(void* const* d_in, const int* in_sizes, int n_in,
                              void* d_out, int out_size, void* d_ws,
                              size_t ws_size, hipStream_t stream)
{
    // inputs: 0:t 1:x 2:edge_row 3:edge_col 4:W 5:b 6:ln_w 7:ln_b
    const float* x   = (const float*)d_in[1];
    const int* erow  = (const int*)d_in[2];
    const int* ecol  = (const int*)d_in[3];
    const float* W   = (const float*)d_in[4];
    const float* b   = (const float*)d_in[5];
    const float* lnw = (const float*)d_in[6];
    const float* lnb = (const float*)d_in[7];
    float* out = (float*)d_out;

    const int nrows = 2 * NNODES;                    // R rows never needed
    const size_t ineed = (size_t)NNODES * HID * sizeof(float);

    if (d_ws != nullptr && ws_size >= ineed) {
        // Fused path: I -> workspace; CSR in out[2N..3N) rows; AI in regs.
        float* Iws = (float*)d_ws;
        float* csr = out + (size_t)2 * NNODES * HID;
        k_gemm_relu<<<(nrows + K1_ROWS - 1) / K1_ROWS, 256, 0, stream>>>(
            x, W, b, out, Iws, csr, nrows);
        k_edges<<<(NNODES * DEG / 4 + 255) / 256, 256, 0, stream>>>(
            erow, ecol, csr);
        k_gather_ln<<<NNODES / 8, 256, 0, stream>>>(
            x, Iws, lnw, lnb, out);
    } else {
        // Fallback: original 3-kernel path, I rows in out[N..2N).
        float* Iptr  = out + (size_t)NNODES * HID;
        float* AIptr = out + (size_t)2 * NNODES * HID;
        k_gemm_relu<<<(nrows + K1_ROWS - 1) / K1_ROWS, 256, 0, stream>>>(
            x, W, b, out, Iptr, nullptr, nrows);
        k_aggregate<<<NGRAPH * BPG, 256, 0, stream>>>(Iptr, erow, ecol, AIptr);
        k_final<<<NNODES / 4, 256, 0, stream>>>(x, lnw, lnb, out);
    }
}